// Round 1
// baseline (25.337 us; speedup 1.0000x reference)
//
#include <hip/hip_runtime.h>

// CustomEmbedding: out[t, :] = sin-row if x[t] < 1000 else weight[x[t], :]
// D = 512 floats per token -> 128 float4 per token, one float4 per thread.

#define DIM 512
#define D4  (DIM / 4)   // 128 float4 per token
#define NUM_NUM 1000

__global__ __launch_bounds__(256) void CustomEmbedding_kernel(
    const int* __restrict__ x,
    const float* __restrict__ weight,
    float* __restrict__ out,
    int n_tok)
{
    int gid = blockIdx.x * 256 + threadIdx.x;   // one float4 per thread
    int tok = gid >> 7;                         // gid / 128
    int d4  = gid & 127;                        // float4 index within the row
    if (tok >= n_tok) return;

    int idx = x[tok];                           // broadcast within the 128-lane group (L1/L2 hit)
    float4 v;
    if (idx < NUM_NUM) {
        // sin((idx/1000) * (i+1)), i = d4*4 .. d4*4+3
        float base = (float)idx * 1e-3f;
        int d = d4 << 2;
        v.x = sinf(base * (float)(d + 1));
        v.y = sinf(base * (float)(d + 2));
        v.z = sinf(base * (float)(d + 3));
        v.w = sinf(base * (float)(d + 4));
    } else {
        v = *reinterpret_cast<const float4*>(weight + (size_t)idx * DIM + (d4 << 2));
    }
    *reinterpret_cast<float4*>(out + (size_t)tok * DIM + (d4 << 2)) = v;
}

extern "C" void kernel_launch(void* const* d_in, const int* in_sizes, int n_in,
                              void* d_out, int out_size, void* d_ws, size_t ws_size,
                              hipStream_t stream) {
    const int*   x      = (const int*)d_in[0];
    const float* weight = (const float*)d_in[1];
    // d_in[2] (num_value) and d_in[3] (is_num) are pure functions of the id; unused.
    float* out = (float*)d_out;

    int n_tok = in_sizes[0];                    // 8 * 4096 = 32768
    long long total_threads = (long long)n_tok * D4;
    int grid = (int)((total_threads + 255) / 256);
    CustomEmbedding_kernel<<<grid, 256, 0, stream>>>(x, weight, out, n_tok);
}

// Round 3
// 24.793 us; speedup vs baseline: 1.0220x; 1.0220x over previous
//
#include <hip/hip_runtime.h>

// CustomEmbedding: out[t, :] = sin-row if x[t] < 1000 else weight[x[t], :]
// D = 512 floats per token -> 128 float4 per token, one float4 per thread.
// Output is write-once streaming -> nontemporal stores (bypass L2, keep
// gathered weight rows L2-resident). Use a clang ext_vector type because
// __builtin_nontemporal_store rejects HIP_vector_type<float,4>.

#define DIM 512
#define D4  (DIM / 4)   // 128 float4 per token
#define NUM_NUM 1000

typedef float floatx4 __attribute__((ext_vector_type(4)));

__global__ __launch_bounds__(256) void CustomEmbedding_kernel(
    const int* __restrict__ x,
    const float* __restrict__ weight,
    float* __restrict__ out,
    int n_tok)
{
    int gid = blockIdx.x * 256 + threadIdx.x;   // one float4 per thread
    int tok = gid >> 7;                         // gid / 128
    int d4  = gid & 127;                        // float4 index within the row
    if (tok >= n_tok) return;

    int idx = x[tok];                           // broadcast within the 128-lane group
    floatx4 v;
    if (idx < NUM_NUM) {
        // sin((idx/1000) * (i+1)), i = d4*4 .. d4*4+3
        float base = (float)idx * 1e-3f;
        int d = d4 << 2;
        v.x = sinf(base * (float)(d + 1));
        v.y = sinf(base * (float)(d + 2));
        v.z = sinf(base * (float)(d + 3));
        v.w = sinf(base * (float)(d + 4));
    } else {
        v = *reinterpret_cast<const floatx4*>(weight + (size_t)idx * DIM + (d4 << 2));
    }
    __builtin_nontemporal_store(v, reinterpret_cast<floatx4*>(out + (size_t)tok * DIM + (d4 << 2)));
}

extern "C" void kernel_launch(void* const* d_in, const int* in_sizes, int n_in,
                              void* d_out, int out_size, void* d_ws, size_t ws_size,
                              hipStream_t stream) {
    const int*   x      = (const int*)d_in[0];
    const float* weight = (const float*)d_in[1];
    // d_in[2] (num_value) and d_in[3] (is_num) are pure functions of the id; unused.
    float* out = (float*)d_out;

    int n_tok = in_sizes[0];                    // 8 * 4096 = 32768
    long long total_threads = (long long)n_tok * D4;
    int grid = (int)((total_threads + 255) / 256);
    CustomEmbedding_kernel<<<grid, 256, 0, stream>>>(x, weight, out, n_tok);
}